// Round 17
// baseline (1239.049 us; speedup 1.0000x reference)
//
#include <hip/hip_runtime.h>
#include <hip/hip_bf16.h>
#include <cstdint>
#include <cstddef>

#define Bsz  256
#define Tn   4096
#define In   8
#define Hn   32
#define TGTn 8

// sigmoid(p) = 1/(1+exp2(ALPHA*p)) with ALPHA = -log2(e)
// tanh path:  exp(2y) = exp2(BETA*y)  with BETA  = 2*log2(e)
#define ALPHA (-1.44269504088896341f)
#define BETA  ( 2.88539008177792682f)

#if __has_builtin(__builtin_amdgcn_exp2f)
__device__ __forceinline__ float exp2f_fast(float x) { return __builtin_amdgcn_exp2f(x); }
#else
__device__ __forceinline__ float exp2f_fast(float x) { return __expf(x * 0.69314718056f); }
#endif
__device__ __forceinline__ float rcpf(float x) { return __builtin_amdgcn_rcpf(x); }

// W = w_ih @ E : [96,8] (raw; scaling applied at gru init)
__global__ void fuse_wih_kernel(const float* __restrict__ w_ih,
                                const float* __restrict__ E,
                                float* __restrict__ Wf) {
    int tid = threadIdx.x;                // 768 threads
    int g = tid >> 3, i = tid & 7;
    float acc = 0.f;
#pragma unroll
    for (int k = 0; k < Hn; ++k)
        acc = fmaf(w_ih[g * Hn + k], E[k * In + i], acc);
    Wf[g * In + i] = acc;
}

#define KEEP(v) asm volatile("" : "+v"(v))

// h-dot term K: 3 independent chains (r,z,n), 2-cyc scalar fmas, no cross-lane.
#define H_FMA(K)                                                                     \
    ar  = fmaf(H##K, wr##K, ar);                                                     \
    az  = fmaf(H##K, wz##K, az);                                                     \
    anh = fmaf(H##K, wn##K, anh);

// reload all 32 h values of this lane's batch from LDS (broadcast reads)
#define RELOAD_H()                                                                   \
  {                                                                                  \
    float4 q0 = *(const float4*)&lds_h[hbase + 0];                                   \
    float4 q1 = *(const float4*)&lds_h[hbase + 4];                                   \
    float4 q2 = *(const float4*)&lds_h[hbase + 8];                                   \
    float4 q3 = *(const float4*)&lds_h[hbase + 12];                                  \
    float4 q4 = *(const float4*)&lds_h[hbase + 16];                                  \
    float4 q5 = *(const float4*)&lds_h[hbase + 20];                                  \
    float4 q6 = *(const float4*)&lds_h[hbase + 24];                                  \
    float4 q7 = *(const float4*)&lds_h[hbase + 28];                                  \
    H0 =q0.x; H1 =q0.y; H2 =q0.z; H3 =q0.w;  H4 =q1.x; H5 =q1.y; H6 =q1.z; H7 =q1.w; \
    H8 =q2.x; H9 =q2.y; H10=q2.z; H11=q2.w;  H12=q3.x; H13=q3.y; H14=q3.z; H15=q3.w; \
    H16=q4.x; H17=q4.y; H18=q4.z; H19=q4.w;  H20=q5.x; H21=q5.y; H22=q5.z; H23=q5.w; \
    H24=q6.x; H25=q6.y; H26=q6.z; H27=q6.w;  H28=q7.x; H29=q7.y; H30=q7.z; H31=q7.w; \
  }

// x-preactivations for the NEXT step from this lane's batch slot pair (XA,XB)
#define PREACT(XA, XB)                                                               \
  {                                                                                  \
    axr = br_s;                                                                      \
    axr = fmaf(XA.x, wxr0, axr); axr = fmaf(XA.y, wxr1, axr);                        \
    axr = fmaf(XA.z, wxr2, axr); axr = fmaf(XA.w, wxr3, axr);                        \
    axr = fmaf(XB.x, wxr4, axr); axr = fmaf(XB.y, wxr5, axr);                        \
    axr = fmaf(XB.z, wxr6, axr); axr = fmaf(XB.w, wxr7, axr);                        \
    axz = bz_s;                                                                      \
    axz = fmaf(XA.x, wxz0, axz); axz = fmaf(XA.y, wxz1, axz);                        \
    axz = fmaf(XA.z, wxz2, axz); axz = fmaf(XA.w, wxz3, axz);                        \
    axz = fmaf(XB.x, wxz4, axz); axz = fmaf(XB.y, wxz5, axz);                        \
    axz = fmaf(XB.z, wxz6, axz); axz = fmaf(XB.w, wxz7, axz);                        \
    axn = bxn_s;                                                                     \
    axn = fmaf(XA.x, wxn0, axn); axn = fmaf(XA.y, wxn1, axn);                        \
    axn = fmaf(XA.z, wxn2, axn); axn = fmaf(XA.w, wxn3, axn);                        \
    axn = fmaf(XB.x, wxn4, axn); axn = fmaf(XB.y, wxn5, axn);                        \
    axn = fmaf(XB.z, wxn6, axn); axn = fmaf(XB.w, wxn7, axn);                        \
  }

// One GRU step. No cross-lane ops: full-K dot per lane, LDS broadcast for h.
#define GRU_STEP(XNA, XNB, XRA, XRB, DO_REFILL)                                      \
  {                                                                                  \
    float ar = axr, az = axz, anh = bhn_s, anx = axn;                                \
    H_FMA(0)  H_FMA(1)  H_FMA(2)  H_FMA(3)  H_FMA(4)  H_FMA(5)  H_FMA(6)  H_FMA(7)  \
    H_FMA(8)  H_FMA(9)  H_FMA(10) H_FMA(11) H_FMA(12) H_FMA(13) H_FMA(14) H_FMA(15) \
    H_FMA(16) H_FMA(17) H_FMA(18) H_FMA(19) H_FMA(20) H_FMA(21) H_FMA(22) H_FMA(23) \
    H_FMA(24) H_FMA(25) H_FMA(26) H_FMA(27) H_FMA(28) H_FMA(29) H_FMA(30) H_FMA(31) \
    float r = rcpf(1.f + exp2f_fast(ar));                                            \
    float z = rcpf(1.f + exp2f_fast(az));                                            \
    float e = exp2f_fast(__builtin_fmaf(r, anh, anx));                               \
    float u = rcpf(e + 1.f);                                                         \
    float n = __builtin_fmaf(-2.f, u, 1.f);                                          \
    hj = __builtin_fmaf(z, hj - n, n);                                               \
    lds_h[lane] = hj;                     /* in-order DS: no barrier (1 wave) */     \
    *latp = hj;                                                                      \
    latp += Hn;                                                                      \
    RELOAD_H()                            /* issue reads; covered below */           \
    PREACT(XNA, XNB)                      /* 24 fmas of cover */                     \
    if (DO_REFILL) {                                                                 \
        XRA = *(const float4*)refp;                                                  \
        XRB = *(const float4*)(refp + 4);                                            \
        refp += In;                                                                  \
    }                                                                                \
  }

// Two batches per wave: lanes 0-31 = batch 2b, lanes 32-63 = batch 2b+1.
// Each lane owns output j of its batch with the FULL K=32 dot -> zero
// cross-lane ops (measured: DPP/permlane cost ~6-8 cyc each on gfx950).
__attribute__((amdgpu_flat_work_group_size(64, 64), amdgpu_waves_per_eu(1, 1)))
__global__ void gru_kernel(const float* __restrict__ x,     // [B,T,8]
                           const float* __restrict__ Wf,    // [96,8] raw w_ih@E
                           const float* __restrict__ w_hh,  // [96,32]
                           const float* __restrict__ b_ih,  // [96]
                           const float* __restrict__ b_hh,  // [96]
                           float* __restrict__ latents) {   // [B,T,32]
    __shared__ __align__(16) float lds_h[2 * Hn];   // [bsel][j]

    const int lane  = threadIdx.x & 63;
    const int bsel  = lane >> 5;
    const int j     = lane & 31;
    const int hbase = bsel * Hn;
    const int b     = blockIdx.x * 2 + bsel;

    // ---- recurrent weights: full row (32 K) per gate, pre-scaled ----
    float wr0,wr1,wr2,wr3,wr4,wr5,wr6,wr7,wr8,wr9,wr10,wr11,wr12,wr13,wr14,wr15,
          wr16,wr17,wr18,wr19,wr20,wr21,wr22,wr23,wr24,wr25,wr26,wr27,wr28,wr29,wr30,wr31;
    float wz0,wz1,wz2,wz3,wz4,wz5,wz6,wz7,wz8,wz9,wz10,wz11,wz12,wz13,wz14,wz15,
          wz16,wz17,wz18,wz19,wz20,wz21,wz22,wz23,wz24,wz25,wz26,wz27,wz28,wz29,wz30,wz31;
    float wn0,wn1,wn2,wn3,wn4,wn5,wn6,wn7,wn8,wn9,wn10,wn11,wn12,wn13,wn14,wn15,
          wn16,wn17,wn18,wn19,wn20,wn21,wn22,wn23,wn24,wn25,wn26,wn27,wn28,wn29,wn30,wn31;
#define LW(P, G, S, Q, N0, N1, N2, N3)                                            \
    {                                                                             \
        float4 q = *(const float4*)&w_hh[((G)*Hn + j)*Hn + 4*(Q)];                \
        P##N0 = (S)*q.x; P##N1 = (S)*q.y; P##N2 = (S)*q.z; P##N3 = (S)*q.w;       \
        KEEP(P##N0); KEEP(P##N1); KEEP(P##N2); KEEP(P##N3);                       \
    }
    LW(wr,0,ALPHA,0, 0,1,2,3)     LW(wr,0,ALPHA,1, 4,5,6,7)
    LW(wr,0,ALPHA,2, 8,9,10,11)   LW(wr,0,ALPHA,3, 12,13,14,15)
    LW(wr,0,ALPHA,4, 16,17,18,19) LW(wr,0,ALPHA,5, 20,21,22,23)
    LW(wr,0,ALPHA,6, 24,25,26,27) LW(wr,0,ALPHA,7, 28,29,30,31)
    LW(wz,1,ALPHA,0, 0,1,2,3)     LW(wz,1,ALPHA,1, 4,5,6,7)
    LW(wz,1,ALPHA,2, 8,9,10,11)   LW(wz,1,ALPHA,3, 12,13,14,15)
    LW(wz,1,ALPHA,4, 16,17,18,19) LW(wz,1,ALPHA,5, 20,21,22,23)
    LW(wz,1,ALPHA,6, 24,25,26,27) LW(wz,1,ALPHA,7, 28,29,30,31)
    LW(wn,2,BETA,0, 0,1,2,3)      LW(wn,2,BETA,1, 4,5,6,7)
    LW(wn,2,BETA,2, 8,9,10,11)    LW(wn,2,BETA,3, 12,13,14,15)
    LW(wn,2,BETA,4, 16,17,18,19)  LW(wn,2,BETA,5, 20,21,22,23)
    LW(wn,2,BETA,6, 24,25,26,27)  LW(wn,2,BETA,7, 28,29,30,31)
#undef LW

    // ---- input weights (8 per gate), pre-scaled ----
    float wxr0,wxr1,wxr2,wxr3,wxr4,wxr5,wxr6,wxr7;
    float wxz0,wxz1,wxz2,wxz3,wxz4,wxz5,wxz6,wxz7;
    float wxn0,wxn1,wxn2,wxn3,wxn4,wxn5,wxn6,wxn7;
#define LX(P, G, S, Q, N0, N1, N2, N3)                                            \
    {                                                                             \
        float4 q = *(const float4*)&Wf[((G)*Hn + j)*In + 4*(Q)];                  \
        P##N0 = (S)*q.x; P##N1 = (S)*q.y; P##N2 = (S)*q.z; P##N3 = (S)*q.w;       \
        KEEP(P##N0); KEEP(P##N1); KEEP(P##N2); KEEP(P##N3);                       \
    }
    LX(wxr,0,ALPHA,0, 0,1,2,3) LX(wxr,0,ALPHA,1, 4,5,6,7)
    LX(wxz,1,ALPHA,0, 0,1,2,3) LX(wxz,1,ALPHA,1, 4,5,6,7)
    LX(wxn,2,BETA,0, 0,1,2,3)  LX(wxn,2,BETA,1, 4,5,6,7)
#undef LX

    // biases, fully folded (no halving — no half_sum in this layout)
    float br_s  = ALPHA * (b_ih[j]        + b_hh[j]);
    float bz_s  = ALPHA * (b_ih[Hn + j]   + b_hh[Hn + j]);
    float bxn_s = BETA  *  b_ih[2*Hn + j];
    float bhn_s = BETA  *  b_hh[2*Hn + j];
    KEEP(br_s); KEEP(bz_s); KEEP(bxn_s); KEEP(bhn_s);

    const float* xb   = x + (size_t)b * Tn * In;         // per-lane (batch) base
    float* latp       = latents + (size_t)b * Tn * Hn + j;
    const float* refp = xb + 4 * In;                     // next refill = x[4]

    float hj = 0.f;
    float H0=0.f,H1=0.f,H2=0.f,H3=0.f,H4=0.f,H5=0.f,H6=0.f,H7=0.f,
          H8=0.f,H9=0.f,H10=0.f,H11=0.f,H12=0.f,H13=0.f,H14=0.f,H15=0.f,
          H16=0.f,H17=0.f,H18=0.f,H19=0.f,H20=0.f,H21=0.f,H22=0.f,H23=0.f,
          H24=0.f,H25=0.f,H26=0.f,H27=0.f,H28=0.f,H29=0.f,H30=0.f,H31=0.f;

    // ---- 4-deep x ring (per-lane batch addresses) ----
    float4 a0 = *(const float4*)&xb[0*In], b0 = *(const float4*)&xb[0*In + 4];
    float4 a1 = *(const float4*)&xb[1*In], b1 = *(const float4*)&xb[1*In + 4];
    float4 a2 = *(const float4*)&xb[2*In], b2 = *(const float4*)&xb[2*In + 4];
    float4 a3 = *(const float4*)&xb[3*In], b3 = *(const float4*)&xb[3*In + 4];

    float axr, axz, axn;
    PREACT(a0, b0)                        // pre-activations for step 0

    // main loop: steps 0..4091 (1023 groups of 4), refilling x[s+4]
#pragma unroll 1
    for (int s0 = 0; s0 < Tn - 4; s0 += 4) {
        GRU_STEP(a1, b1, a0, b0, true)
        GRU_STEP(a2, b2, a1, b1, true)
        GRU_STEP(a3, b3, a2, b2, true)
        GRU_STEP(a0, b0, a3, b3, true)
    }
    // epilogue: steps 4092..4095 (slots hold x[4092..4095]); no refills
    GRU_STEP(a1, b1, a0, b0, false)
    GRU_STEP(a2, b2, a1, b1, false)
    GRU_STEP(a3, b3, a2, b2, false)
    GRU_STEP(a0, b0, a3, b3, false)
}
#undef KEEP

// outputs[b,t,o] = sum_h latents[b,t,h] * E[h,o]
__global__ void decode_kernel(const float* __restrict__ lat,
                              const float* __restrict__ E,
                              float* __restrict__ out) {
    __shared__ float ldsE[Hn * TGTn];
    int tid = threadIdx.x;
    if (tid < Hn * TGTn) ldsE[tid] = E[tid];
    __syncthreads();
    size_t idx = (size_t)blockIdx.x * 256 + tid;   // over B*T*8
    int o      = (int)(idx & (TGTn - 1));
    size_t row = idx >> 3;
    const float* lrow = lat + row * Hn;
    float acc = 0.f;
#pragma unroll
    for (int h = 0; h < Hn; ++h)
        acc = fmaf(lrow[h], ldsE[h * TGTn + o], acc);
    out[idx] = acc;
}

extern "C" void kernel_launch(void* const* d_in, const int* in_sizes, int n_in,
                              void* d_out, int out_size, void* d_ws, size_t ws_size,
                              hipStream_t stream) {
    const float* x    = (const float*)d_in[0];
    const float* E    = (const float*)d_in[1];
    const float* w_ih = (const float*)d_in[2];
    const float* w_hh = (const float*)d_in[3];
    const float* b_ih = (const float*)d_in[4];
    const float* b_hh = (const float*)d_in[5];

    float* out = (float*)d_out;                          // [B,T,8]
    float* lat = out + (size_t)Bsz * Tn * TGTn;          // [B,T,32]
    float* Wf  = (float*)d_ws;                           // [96,8]

    fuse_wih_kernel<<<1, 768, 0, stream>>>(w_ih, E, Wf);
    gru_kernel<<<Bsz / 2, 64, 0, stream>>>(x, Wf, w_hh, b_ih, b_hh, lat);
    decode_kernel<<<(Bsz * Tn * TGTn) / 256, 256, 0, stream>>>(lat, E, out);
}

// Round 18
// 989.356 us; speedup vs baseline: 1.2524x; 1.2524x over previous
//
#include <hip/hip_runtime.h>
#include <hip/hip_bf16.h>
#include <cstdint>
#include <cstddef>

#define Bsz  256
#define Tn   4096
#define In   8
#define Hn   32
#define TGTn 8

// sigmoid(p) = 1/(1+exp2(ALPHA*p)) with ALPHA = -log2(e)
// tanh path:  exp(2y) = exp2(BETA*y)  with BETA  = 2*log2(e)
#define ALPHA (-1.44269504088896341f)
#define BETA  ( 2.88539008177792682f)

#if __has_builtin(__builtin_amdgcn_exp2f)
__device__ __forceinline__ float exp2f_fast(float x) { return __builtin_amdgcn_exp2f(x); }
#else
__device__ __forceinline__ float exp2f_fast(float x) { return __expf(x * 0.69314718056f); }
#endif
__device__ __forceinline__ float rcpf(float x) { return __builtin_amdgcn_rcpf(x); }

// DPP row_ror via builtin — INIT-TIME PROBE ONLY (same hw op as the asm fmacs).
template<int N>
__device__ __forceinline__ float dpp_ror(float x) {
    int xi = __float_as_int(x);
    int r = __builtin_amdgcn_update_dpp(xi, xi, 0x120 + N, 0xF, 0xF, false);
    return __int_as_float(r);
}

// x_l + x_{l^16}: sum of both permlane16_swap outputs (order-proof).
__device__ __forceinline__ float halfsum16(float x) {
    auto r = __builtin_amdgcn_permlane16_swap(__float_as_int(x), __float_as_int(x),
                                              false, false);
    return __int_as_float((int)r[0]) + __int_as_float((int)r[1]);
}

// fmac with the h-gather FUSED as a DPP row-rotate on src0.
// NON-volatile: pure "+v" dataflow, so the scheduler may interleave
// surrounding loads/stores/x-fmas into the DPP stream (r16 had volatile,
// which pinned all 48 fmacs into one rigid unschedulable block).
#define FMAC_DPP(acc, h, w, N)                                                       \
    asm("v_fmac_f32 %0, %1, %2 row_ror:" #N " row_mask:0xf bank_mask:0xf"            \
        : "+v"(acc) : "v"(h), "v"(w))
// first DPP after the hsrc update: keep volatile + s_nop to guarantee the
// VALU-write -> DPP-read wait states regardless of scheduling.
#define FMAC_DPP_FIRST(acc, h, w, N)                                                 \
    asm volatile("s_nop 1\n\t"                                                       \
                 "v_fmac_f32 %0, %1, %2 row_ror:" #N " row_mask:0xf bank_mask:0xf"   \
                 : "+v"(acc) : "v"(h), "v"(w))

// W = w_ih @ E : [96,8] (raw; scaling applied at gru init)
__global__ void fuse_wih_kernel(const float* __restrict__ w_ih,
                                const float* __restrict__ E,
                                float* __restrict__ Wf) {
    int tid = threadIdx.x;                // 768 threads
    int g = tid >> 3, i = tid & 7;
    float acc = 0.f;
#pragma unroll
    for (int k = 0; k < Hn; ++k)
        acc = fmaf(w_ih[g * Hn + k], E[k * In + i], acc);
    Wf[g * In + i] = acc;
}

// round-robin the three gate chains so dependent fmacs are 3 instrs apart
#define HROT3(N)                                                                     \
    FMAC_DPP(ar,  hsrc, whr##N, N);                                                  \
    FMAC_DPP(az,  hsrc, whz##N, N);                                                  \
    FMAC_DPP(anh, hsrc, whn##N, N);

// One GRU step. XQ = this lane-half's 4 x-channels for step s (float4);
// XRQ = ring slot refilled with x[s+4] when DO_REFILL.
// hsrc = h[16*rowpar + (lane&15)] per lane.
#define GRU_STEP(XQ, XRQ, DO_REFILL)                                                 \
  {                                                                                  \
    /* x-dots: 4 channels per lane-half; all three go through halfsum16 */           \
    float ar = br_h, az = bz_h, anx = bxn_h, anh = bhn_h;                            \
    ar  = fmaf(XQ.x, wxr0, ar);  ar  = fmaf(XQ.y, wxr1, ar);                         \
    ar  = fmaf(XQ.z, wxr2, ar);  ar  = fmaf(XQ.w, wxr3, ar);                         \
    az  = fmaf(XQ.x, wxz0, az);  az  = fmaf(XQ.y, wxz1, az);                         \
    az  = fmaf(XQ.z, wxz2, az);  az  = fmaf(XQ.w, wxz3, az);                         \
    anx = fmaf(XQ.x, wxn0, anx); anx = fmaf(XQ.y, wxn1, anx);                        \
    anx = fmaf(XQ.z, wxn2, anx); anx = fmaf(XQ.w, wxn3, anx);                        \
    float cxn = halfsum16(anx);                                                      \
    /* h-dots with gather fused via DPP; m=0 plain (spaces the hazard too) */        \
    ar  = fmaf(hsrc, whr0, ar);                                                      \
    az  = fmaf(hsrc, whz0, az);                                                      \
    anh = fmaf(hsrc, whn0, anh);                                                     \
    FMAC_DPP_FIRST(ar, hsrc, whr1, 1);                                               \
    FMAC_DPP(az,  hsrc, whz1, 1);                                                    \
    FMAC_DPP(anh, hsrc, whn1, 1);                                                    \
    HROT3(2)  HROT3(3)  HROT3(4)  HROT3(5)  HROT3(6)  HROT3(7)  HROT3(8)             \
    HROT3(9)  HROT3(10) HROT3(11) HROT3(12) HROT3(13) HROT3(14) HROT3(15)            \
    float cr  = halfsum16(ar);            /* ALPHA*(xdot+hdot+bias) */               \
    float cz  = halfsum16(az);                                                       \
    float chn = halfsum16(anh);           /* BETA*(hdot+b_hn)       */               \
    float r = rcpf(1.f + exp2f_fast(cr));                                            \
    float z = rcpf(1.f + exp2f_fast(cz));                                            \
    float e = exp2f_fast(__builtin_fmaf(r, chn, cxn));                               \
    float u = rcpf(e + 1.f);                                                         \
    float n = __builtin_fmaf(-2.f, u, 1.f);                                          \
    hj = __builtin_fmaf(z, hj - n, n);                                               \
    /* redistribute: hsrc = h[16*rowpar + (lane&15)] (probed selection) */           \
    {                                                                                \
        auto rr = __builtin_amdgcn_permlane32_swap(__float_as_int(hj),               \
                                                   __float_as_int(hj),               \
                                                   false, false);                    \
        float s0 = __int_as_float((int)rr[0]);                                       \
        float s1 = __int_as_float((int)rr[1]);                                       \
        hsrc = pickr1 ? s1 : s0;                                                     \
    }                                                                                \
    latb_u[j] = hj;                       /* dup x2 per j: same value, benign */     \
    latb_u += Hn;                         /* uniform -> SALU */                      \
    if (DO_REFILL) {                                                                 \
        XRQ = *(const float4*)refp;       /* this half's 4 channels of x[s+4] */     \
        refp += In;                                                                  \
    }                                                                                \
  }

#define KEEP(v) asm volatile("" : "+v"(v))
__attribute__((amdgpu_flat_work_group_size(64, 64), amdgpu_waves_per_eu(1, 1)))
__global__ void gru_kernel(const float* __restrict__ x,     // [B,T,8]
                           const float* __restrict__ Wf,    // [96,8] raw w_ih@E
                           const float* __restrict__ w_hh,  // [96,32]
                           const float* __restrict__ b_ih,  // [96]
                           const float* __restrict__ b_hh,  // [96]
                           float* __restrict__ latents) {   // [B,T,32]
    const int lane   = threadIdx.x & 63;
    const int rowpar = (lane >> 4) & 1;             // K-half = DPP-row parity
    const int j      = (lane & 15) | ((lane >> 1) & 16);  // invariant under ^16
    const int b      = blockIdx.x;

    // ---- probe 1: row_ror permutation (within-row h index per m) ----
    int rho[16];
    {
        float q = (float)(lane & 15);
        rho[0]  = lane & 15;
        rho[1]  = (int)dpp_ror<1>(q);   rho[2]  = (int)dpp_ror<2>(q);
        rho[3]  = (int)dpp_ror<3>(q);   rho[4]  = (int)dpp_ror<4>(q);
        rho[5]  = (int)dpp_ror<5>(q);   rho[6]  = (int)dpp_ror<6>(q);
        rho[7]  = (int)dpp_ror<7>(q);   rho[8]  = (int)dpp_ror<8>(q);
        rho[9]  = (int)dpp_ror<9>(q);   rho[10] = (int)dpp_ror<10>(q);
        rho[11] = (int)dpp_ror<11>(q);  rho[12] = (int)dpp_ror<12>(q);
        rho[13] = (int)dpp_ror<13>(q);  rho[14] = (int)dpp_ror<14>(q);
        rho[15] = (int)dpp_ror<15>(q);
    }
    // ---- probe 2: permlane32_swap output order (which slot = partner) ----
    bool pickr1;
    {
        float t = (float)lane;
        auto rr = __builtin_amdgcn_permlane32_swap(__float_as_int(t),
                                                   __float_as_int(t),
                                                   false, false);
        bool r0_own    = ((int)__int_as_float((int)rr[0]) == lane);
        bool use_swap  = (rowpar != ((lane >> 5) & 1));  // rows 1,2 take partner
        pickr1 = (use_swap == r0_own);
    }

    // ---- recurrent weights: m-th fmac reads h[16*rowpar + rho[m]] ----
    float whr0,whr1,whr2,whr3,whr4,whr5,whr6,whr7,whr8,whr9,whr10,whr11,whr12,whr13,whr14,whr15;
    float whz0,whz1,whz2,whz3,whz4,whz5,whz6,whz7,whz8,whz9,whz10,whz11,whz12,whz13,whz14,whz15;
    float whn0,whn1,whn2,whn3,whn4,whn5,whn6,whn7,whn8,whn9,whn10,whn11,whn12,whn13,whn14,whn15;
#define LOADW(M)                                                                  \
    {                                                                             \
        const int c = rowpar * 16 + rho[M];                                       \
        whr##M = ALPHA * w_hh[(0*Hn + j)*Hn + c];                                 \
        whz##M = ALPHA * w_hh[(1*Hn + j)*Hn + c];                                 \
        whn##M = BETA  * w_hh[(2*Hn + j)*Hn + c];                                 \
        KEEP(whr##M); KEEP(whz##M); KEEP(whn##M);                                 \
    }
    LOADW(0) LOADW(1) LOADW(2)  LOADW(3)  LOADW(4)  LOADW(5)  LOADW(6)  LOADW(7)
    LOADW(8) LOADW(9) LOADW(10) LOADW(11) LOADW(12) LOADW(13) LOADW(14) LOADW(15)
#undef LOADW

    // ---- input weights: this lane-half's 4 of 8 channels; NOT halved
    //      (each half covers distinct i; halfsum16 sums the two halves) ----
    float wxr0,wxr1,wxr2,wxr3;
    float wxz0,wxz1,wxz2,wxz3;
    float wxn0,wxn1,wxn2,wxn3;
#define LOADX(I)                                                                  \
    wxr##I = ALPHA * Wf[(0*Hn + j)*In + rowpar*4 + I];                            \
    wxz##I = ALPHA * Wf[(1*Hn + j)*In + rowpar*4 + I];                            \
    wxn##I = BETA  * Wf[(2*Hn + j)*In + rowpar*4 + I];                            \
    KEEP(wxr##I); KEEP(wxz##I); KEEP(wxn##I);
    LOADX(0) LOADX(1) LOADX(2) LOADX(3)
#undef LOADX

    // biases: ALL pre-halved (every pre-activation now passes halfsum16)
    float br_h  = 0.5f * ALPHA * (b_ih[j]        + b_hh[j]);
    float bz_h  = 0.5f * ALPHA * (b_ih[Hn + j]   + b_hh[Hn + j]);
    float bxn_h = 0.5f * BETA * b_ih[2*Hn + j];
    float bhn_h = 0.5f * BETA * b_hh[2*Hn + j];
    KEEP(br_h); KEEP(bz_h); KEEP(bxn_h); KEEP(bhn_h);

    const float* xb   = x + (size_t)b * Tn * In + rowpar * 4;  // per-half base
    float* latb_u     = latents + (size_t)b * Tn * Hn;         // uniform base
    const float* refp = xb + 4 * In;                           // next refill = x[4]

    float hj = 0.f;
    float hsrc = 0.f;                                          // h == 0 at t=0

    // ---- 4-deep x ring: ONE float4 (this half's channels) per slot ----
    float4 x0 = *(const float4*)&xb[0*In];
    float4 x1 = *(const float4*)&xb[1*In];
    float4 x2 = *(const float4*)&xb[2*In];
    float4 x3 = *(const float4*)&xb[3*In];

    // main loop: steps 0..4091 (1023 groups of 4), refilling x[s+4]
#pragma unroll 1
    for (int s0 = 0; s0 < Tn - 4; s0 += 4) {
        GRU_STEP(x0, x0, true)
        GRU_STEP(x1, x1, true)
        GRU_STEP(x2, x2, true)
        GRU_STEP(x3, x3, true)
    }
    // epilogue: steps 4092..4095 (slots hold x[4092..4095]); no refills
    GRU_STEP(x0, x0, false)
    GRU_STEP(x1, x1, false)
    GRU_STEP(x2, x2, false)
    GRU_STEP(x3, x3, false)
}
#undef KEEP

// outputs[b,t,o] = sum_h latents[b,t,h] * E[h,o]
__global__ void decode_kernel(const float* __restrict__ lat,
                              const float* __restrict__ E,
                              float* __restrict__ out) {
    __shared__ float ldsE[Hn * TGTn];
    int tid = threadIdx.x;
    if (tid < Hn * TGTn) ldsE[tid] = E[tid];
    __syncthreads();
    size_t idx = (size_t)blockIdx.x * 256 + tid;   // over B*T*8
    int o      = (int)(idx & (TGTn - 1));
    size_t row = idx >> 3;
    const float* lrow = lat + row * Hn;
    float acc = 0.f;
#pragma unroll
    for (int h = 0; h < Hn; ++h)
        acc = fmaf(lrow[h], ldsE[h * TGTn + o], acc);
    out[idx] = acc;
}

extern "C" void kernel_launch(void* const* d_in, const int* in_sizes, int n_in,
                              void* d_out, int out_size, void* d_ws, size_t ws_size,
                              hipStream_t stream) {
    const float* x    = (const float*)d_in[0];
    const float* E    = (const float*)d_in[1];
    const float* w_ih = (const float*)d_in[2];
    const float* w_hh = (const float*)d_in[3];
    const float* b_ih = (const float*)d_in[4];
    const float* b_hh = (const float*)d_in[5];

    float* out = (float*)d_out;                          // [B,T,8]
    float* lat = out + (size_t)Bsz * Tn * TGTn;          // [B,T,32]
    float* Wf  = (float*)d_ws;                           // [96,8]

    fuse_wih_kernel<<<1, 768, 0, stream>>>(w_ih, E, Wf);
    gru_kernel<<<Bsz, 64, 0, stream>>>(x, Wf, w_hh, b_ih, b_hh, lat);
    decode_kernel<<<(Bsz * Tn * TGTn) / 256, 256, 0, stream>>>(lat, E, out);
}